// Round 5
// baseline (267.002 us; speedup 1.0000x reference)
//
#include <hip/hip_runtime.h>
#include <hip/hip_bf16.h>

typedef short bf16x8 __attribute__((ext_vector_type(8)));
typedef float f32x4 __attribute__((ext_vector_type(4)));
typedef ushort ushort8_t __attribute__((ext_vector_type(8)));

__device__ __forceinline__ float bf2f(ushort u) {
    union { unsigned int i; float f; } c; c.i = ((unsigned int)u) << 16; return c.f;
}
__device__ __forceinline__ ushort f2bf(float f) {
    union { float f; unsigned int i; } c; c.f = f;
    unsigned int x = c.i;
    return (ushort)((x + 0x7fffu + ((x >> 16) & 1u)) >> 16);  // RNE
}

#define GLOAD_LDS16(g, l) __builtin_amdgcn_global_load_lds( \
    (const __attribute__((address_space(1))) unsigned int*)(g), \
    (__attribute__((address_space(3))) unsigned int*)(l), 16, 0, 0)

// ---------------- prep: fp32 -> bf16 (vectorized) ----------------
__global__ __launch_bounds__(256) void k_cvt_bf16(const float* __restrict__ in,
                                                  ushort* __restrict__ out, int n4) {
    int i = blockIdx.x * 256 + threadIdx.x;
    if (i < n4) {
        float4 v = ((const float4*)in)[i];
        ushort4 o;
        o.x = f2bf(v.x); o.y = f2bf(v.y); o.z = f2bf(v.z); o.w = f2bf(v.w);
        ((ushort4*)out)[i] = o;
    }
}

// ---------------- prep: [K][N] fp32 -> [N][K] bf16 ----------------
__global__ __launch_bounds__(256) void k_transpose_cvt(const float* __restrict__ in,
                                                       ushort* __restrict__ out,
                                                       int K, int N) {
    __shared__ float tile[32][33];
    int n0 = blockIdx.x * 32, k0 = blockIdx.y * 32;
    int tx = threadIdx.x, ty = threadIdx.y;  // blockDim (32,8)
    #pragma unroll
    for (int i = 0; i < 32; i += 8)
        tile[ty + i][tx] = in[(size_t)(k0 + ty + i) * N + n0 + tx];
    __syncthreads();
    #pragma unroll
    for (int i = 0; i < 32; i += 8)
        out[(size_t)(n0 + ty + i) * K + k0 + tx] = f2bf(tile[tx][ty + i]);
}

// ================= 256x256 8-phase GEMM, 4 waves (K=1024 fixed) =========
// C[M][N] = A[M][1024]*Bt[N][1024]^T + bias.  4 waves in a 2x2 grid, each
// owning a 128x128 output tile (M_rep=8, N_rep=8): 16 ds_read_b128 per 64
// MFMAs -- 2x the MFMA:LDS-byte ratio of the 8-wave layout (LDS-read-BW was
// the measured 41%-util limiter).  Same proven 8-phase schedule / swizzle /
// stage order; loads-per-stage = 4 (256 thr), so counted vmcnt scales 2x
// (VM16/VM20).  Swizzle: 16B chunk ^= (row>>1)&3 on pre-swizzled global
// source + ds_read addr (verified conflict-free: SQ_LDS_BANK_CONFLICT==0).
// Read-ahead: phase p issues ds_reads for p+1 into alternate frag regs; no
// lgkmcnt(0) -- compiler emits precise counted lgkm waits.

#define LDSA(c,kk) (lds + (c)*65536 + (kk)*16384)
#define LDSB(c,kk) (lds + (c)*65536 + 32768 + (kk)*16384)
#define STAGE_A(c,kk,col) do { \
    GLOAD_LDS16(gA0 + (col), LDSA(c,kk) + wave*1024); \
    GLOAD_LDS16(gA1 + (col), LDSA(c,kk) + 4096 + wave*1024); \
    GLOAD_LDS16(gA2 + (col), LDSA(c,kk) + 8192 + wave*1024); \
    GLOAD_LDS16(gA3 + (col), LDSA(c,kk) + 12288 + wave*1024); } while(0)
#define STAGE_B(c,kk,col) do { \
    GLOAD_LDS16(gB0 + (col), LDSB(c,kk) + wave*1024); \
    GLOAD_LDS16(gB1 + (col), LDSB(c,kk) + 4096 + wave*1024); \
    GLOAD_LDS16(gB2 + (col), LDSB(c,kk) + 8192 + wave*1024); \
    GLOAD_LDS16(gB3 + (col), LDSB(c,kk) + 12288 + wave*1024); } while(0)
#define READ_AF(S,c,kk) do { const char* _p = LDSA(c,kk) + aoff; \
    _Pragma("unroll") for (int m = 0; m < 8; ++m) S[m] = *(const bf16x8*)(_p + m*1024); } while(0)
#define READ_B4(c,kk,nh) do { const char* _p = LDSB(c,kk) + boff; \
    _Pragma("unroll") for (int j = 0; j < 4; ++j) \
        bfr[(nh)*4+j] = *(const bf16x8*)(_p + ((nh)*4+j)*1024); } while(0)
#define MF32(S,nh) do { __builtin_amdgcn_s_setprio(1); \
    _Pragma("unroll") for (int m = 0; m < 8; ++m) \
    _Pragma("unroll") for (int n = 0; n < 4; ++n) \
    acc[m][(nh)*4+n] = __builtin_amdgcn_mfma_f32_16x16x32_bf16(S[m], bfr[(nh)*4+n], acc[m][(nh)*4+n], 0,0,0); \
    __builtin_amdgcn_s_setprio(0); } while(0)

#define BAR __builtin_amdgcn_s_barrier()
#define FENCE asm volatile("" ::: "memory")
#define VM16 asm volatile("s_waitcnt vmcnt(16)" ::: "memory")
#define VM20 asm volatile("s_waitcnt vmcnt(20)" ::: "memory")
#define VM0  asm volatile("s_waitcnt vmcnt(0)" ::: "memory")

// Phase layout: [reads for p+1][stage][MFMA(p)][vmcnt][BAR]
// Consumption: ph1-2 buf0/kk0 (afA), ph3-4 buf0/kk1 (afB),
//              ph5-6 buf1/kk0 (afA), ph7-8 buf1/kk1 (afB).
#define ITERX(kb, LAST) do { \
  /*1*/ FENCE; READ_B4(0,0,1);                   STAGE_B(1,1,(kb)+96);              MF32(afA,0); if(LAST) VM0; else VM16; FENCE; BAR; \
  /*2*/ FENCE; READ_AF(afB,0,1); READ_B4(0,1,0); if(!(LAST)) STAGE_A(0,0,(kb)+128); MF32(afA,1); if(!(LAST)) VM20;       FENCE; BAR; \
  /*3*/ FENCE; READ_B4(0,1,1);                   if(!(LAST)) STAGE_B(0,0,(kb)+128); MF32(afB,0); if(!(LAST)) VM16;       FENCE; BAR; \
  /*4*/ FENCE; READ_AF(afA,1,0); READ_B4(1,0,0); if(!(LAST)) STAGE_A(0,1,(kb)+160); MF32(afB,1); if(!(LAST)) VM20;       FENCE; BAR; \
  /*5*/ FENCE; READ_B4(1,0,1);                   if(!(LAST)) STAGE_B(0,1,(kb)+160); MF32(afA,0); if(!(LAST)) VM16;       FENCE; BAR; \
  /*6*/ FENCE; READ_AF(afB,1,1); READ_B4(1,1,0); if(!(LAST)) STAGE_A(1,0,(kb)+192); MF32(afA,1); if(!(LAST)) VM20;       FENCE; BAR; \
  /*7*/ FENCE; READ_B4(1,1,1);                   if(!(LAST)) STAGE_B(1,0,(kb)+192); MF32(afB,0); if(!(LAST)) VM16;       FENCE; BAR; \
  /*8*/ FENCE; if(!(LAST)) { READ_AF(afA,0,0); READ_B4(0,0,0); STAGE_A(1,1,(kb)+224); } MF32(afB,1); if(!(LAST)) VM20;   FENCE; BAR; \
} while(0)

template<bool OUT_BF16>
__global__ __launch_bounds__(256, 1) void k_gemm256(const ushort* __restrict__ A,
                                                    const ushort* __restrict__ Bt,
                                                    const float* __restrict__ bias,
                                                    void* __restrict__ Cout,
                                                    int N, int NTN) {
    __shared__ __align__(16) char lds[131072];
    const int K = 1024;
    const int tid = threadIdx.x;
    const int wave = tid >> 6, lane = tid & 63;
    const int wr = wave >> 1, wc = wave & 1;
    const int r = lane & 15, q = lane >> 4;

    // bijective XCD swizzle (gridDim.x % 8 == 0)
    const int cpx = gridDim.x >> 3, wg = blockIdx.x;
    const int swz = (wg & 7) * cpx + (wg >> 3);
    const int tm = swz / NTN, tn = swz - tm * NTN;
    const int bm = tm * 256, bn = tn * 256;

    // staging lane pointers (source pre-swizzled: chunk ^= (row>>1)&3)
    const int srow = tid >> 2;                      // 0..63
    const int c16l = (tid & 3) ^ ((srow >> 1) & 3);
    const ushort* gA0 = A  + (size_t)(bm + srow) * K + c16l * 8;
    const ushort* gA1 = gA0 + (size_t)64 * K;
    const ushort* gA2 = gA0 + (size_t)128 * K;
    const ushort* gA3 = gA0 + (size_t)192 * K;
    const ushort* gB0 = Bt + (size_t)(bn + srow) * K + c16l * 8;
    const ushort* gB1 = gB0 + (size_t)64 * K;
    const ushort* gB2 = gB0 + (size_t)128 * K;
    const ushort* gB3 = gB0 + (size_t)192 * K;

    // swizzled ds_read offsets: chunk = q ^ ((row>>1)&3)
    const int chunkx = ((q ^ ((r >> 1) & 3)) << 4);
    const int aoff = (wr * 128 + r) * 64 + chunkx;
    const int boff = (wc * 128 + r) * 64 + chunkx;

    f32x4 acc[8][8];
    #pragma unroll
    for (int m = 0; m < 8; ++m)
        #pragma unroll
        for (int n = 0; n < 8; ++n)
            acc[m][n] = (f32x4){0.f, 0.f, 0.f, 0.f};
    bf16x8 afA[8], afB[8], bfr[8];

    // prologue: tile0 (all 4 halves), tile1 (Ak0,Bk0,Ak1); then pre-read
    // frags for ITER1 phase 1 (A(0,0) + B(0,0) low half).
    STAGE_A(0,0,0);  STAGE_B(0,0,0);
    STAGE_A(0,1,32); STAGE_B(0,1,32);
    STAGE_A(1,0,64); STAGE_B(1,0,64);
    STAGE_A(1,1,96);
    VM20; BAR; FENCE;
    READ_AF(afA,0,0); READ_B4(0,0,0);

    #pragma unroll 1
    for (int i = 0; i < 7; ++i) { ITERX(i * 128, 0); }
    ITERX(896, 1);

    float* Cf = (float*)Cout;
    ushort* Cb = (ushort*)Cout;
    #pragma unroll
    for (int m = 0; m < 8; ++m) {
        int row0 = bm + wr * 128 + m * 16 + q * 4;
        #pragma unroll
        for (int n = 0; n < 8; ++n) {
            int col = bn + wc * 128 + n * 16 + r;
            float bv = bias[col];
            #pragma unroll
            for (int j = 0; j < 4; ++j) {
                float v = acc[m][n][j] + bv;
                if (OUT_BF16) Cb[(size_t)(row0 + j) * N + col] = f2bf(v);
                else          Cf[(size_t)(row0 + j) * N + col] = v;
            }
        }
    }
}

// ---------------- per-token head-mixing attention ----------------
// qkv row layout: col = h*192 + {0..63 q, 64..127 k, 128..191 v}
__global__ __launch_bounds__(256) void k_attn(const ushort* __restrict__ qkv,
                                              ushort* __restrict__ ctx) {
    __shared__ float sq[16 * 193];   // [h][192], stride 193 (bank-conflict-free)
    __shared__ float sa[16][17];
    const int t = threadIdx.x;
    const size_t tok = blockIdx.x;
    const ushort* row = qkv + tok * 3072;
    #pragma unroll
    for (int j = 0; j < 2; ++j) {
        int idx = t + j * 256;            // 16B chunk index, 384 total
        if (idx < 384) {
            ushort8_t v = ((const ushort8_t*)row)[idx];
            int i = idx * 8;
            int h = i / 192, c = i - h * 192;
            float* dst = sq + h * 193 + c;
            #pragma unroll
            for (int e = 0; e < 8; ++e) dst[e] = bf2f(v[e]);
        }
    }
    __syncthreads();
    const int h = t >> 4, g = t & 15;
    const float* qp = sq + h * 193;
    const float* kp = sq + g * 193 + 64;
    float s = 0.f;
    #pragma unroll
    for (int d = 0; d < 64; ++d) s += qp[d] * kp[d];
    s *= 0.125f;
    float mx = s;
    #pragma unroll
    for (int o = 8; o; o >>= 1) mx = fmaxf(mx, __shfl_xor(mx, o, 16));
    float e = __expf(s - mx);
    float sum = e;
    #pragma unroll
    for (int o = 8; o; o >>= 1) sum += __shfl_xor(sum, o, 16);
    sa[h][g] = e / sum;
    __syncthreads();
    #pragma unroll
    for (int j = 0; j < 4; ++j) {
        int o = t + j * 256;
        int oh = o >> 6, od = o & 63;
        float c = 0.f;
        #pragma unroll
        for (int gg = 0; gg < 16; ++gg) c += sa[oh][gg] * sq[gg * 193 + 128 + od];
        ctx[tok * 1024 + o] = f2bf(c);
    }
}

extern "C" void kernel_launch(void* const* d_in, const int* in_sizes, int n_in,
                              void* d_out, int out_size, void* d_ws, size_t ws_size,
                              hipStream_t stream) {
    const float* x     = (const float*)d_in[0];
    const float* W_qkv = (const float*)d_in[1];
    const float* b_qkv = (const float*)d_in[2];
    const float* W_out = (const float*)d_in[3];
    const float* b_out = (const float*)d_in[4];

    const int M = 16384, D = 1024, N3 = 3072;

    ushort* xb   = (ushort*)d_ws;
    ushort* wqkT = xb + (size_t)M * D;
    ushort* woT  = wqkT + (size_t)N3 * D;
    ushort* qkv  = woT + (size_t)D * D;
    ushort* ctx  = xb;  // xb dead after GEMM1; reuse for context

    hipLaunchKernelGGL(k_cvt_bf16, dim3((M * D / 4 + 255) / 256), dim3(256), 0, stream,
                       x, xb, M * D / 4);
    hipLaunchKernelGGL(k_transpose_cvt, dim3(N3 / 32, D / 32), dim3(32, 8), 0, stream,
                       W_qkv, wqkT, D, N3);
    hipLaunchKernelGGL(k_transpose_cvt, dim3(D / 32, D / 32), dim3(32, 8), 0, stream,
                       W_out, woT, D, D);
    hipLaunchKernelGGL((k_gemm256<true>), dim3((N3 / 256) * (M / 256)), dim3(256), 0, stream,
                       xb, wqkT, b_qkv, (void*)qkv, N3, N3 / 256);
    hipLaunchKernelGGL(k_attn, dim3(M), dim3(256), 0, stream, qkv, ctx);
    hipLaunchKernelGGL((k_gemm256<false>), dim3((D / 256) * (M / 256)), dim3(256), 0, stream,
                       ctx, woT, b_out, d_out, D, D / 256);
}

// Round 6
// 208.649 us; speedup vs baseline: 1.2797x; 1.2797x over previous
//
#include <hip/hip_runtime.h>
#include <hip/hip_bf16.h>

typedef short bf16x8 __attribute__((ext_vector_type(8)));
typedef float f32x4 __attribute__((ext_vector_type(4)));
typedef ushort ushort8_t __attribute__((ext_vector_type(8)));

__device__ __forceinline__ float bf2f(ushort u) {
    union { unsigned int i; float f; } c; c.i = ((unsigned int)u) << 16; return c.f;
}
__device__ __forceinline__ ushort f2bf(float f) {
    union { float f; unsigned int i; } c; c.f = f;
    unsigned int x = c.i;
    return (ushort)((x + 0x7fffu + ((x >> 16) & 1u)) >> 16);  // RNE
}

#define GLOAD_LDS16(g, l) __builtin_amdgcn_global_load_lds( \
    (const __attribute__((address_space(1))) unsigned int*)(g), \
    (__attribute__((address_space(3))) unsigned int*)(l), 16, 0, 0)

// ---------------- prep: fp32 -> bf16 (vectorized) ----------------
__global__ __launch_bounds__(256) void k_cvt_bf16(const float* __restrict__ in,
                                                  ushort* __restrict__ out, int n4) {
    int i = blockIdx.x * 256 + threadIdx.x;
    if (i < n4) {
        float4 v = ((const float4*)in)[i];
        ushort4 o;
        o.x = f2bf(v.x); o.y = f2bf(v.y); o.z = f2bf(v.z); o.w = f2bf(v.w);
        ((ushort4*)out)[i] = o;
    }
}

// ---------------- prep: [K][N] fp32 -> [N][K] bf16 ----------------
__global__ __launch_bounds__(256) void k_transpose_cvt(const float* __restrict__ in,
                                                       ushort* __restrict__ out,
                                                       int K, int N) {
    __shared__ float tile[32][33];
    int n0 = blockIdx.x * 32, k0 = blockIdx.y * 32;
    int tx = threadIdx.x, ty = threadIdx.y;  // blockDim (32,8)
    #pragma unroll
    for (int i = 0; i < 32; i += 8)
        tile[ty + i][tx] = in[(size_t)(k0 + ty + i) * N + n0 + tx];
    __syncthreads();
    #pragma unroll
    for (int i = 0; i < 32; i += 8)
        out[(size_t)(n0 + ty + i) * K + k0 + tx] = f2bf(tile[tx][ty + i]);
}

// ================= 256x256 8-phase GEMM (K=1024 fixed) =================
// 8 waves (2Mx4N), wave tile 128x64, BK=64, LDS 128KB (2buf x 2kk x A,B).
// Swizzle: 16B chunk ^= (row>>1)&3 on pre-swizzled global source + ds_read
// addr (verified conflict-free: SQ_LDS_BANK_CONFLICT == 0).
// Overlap structure: phase p issues ds_reads for phase p+1 (alternate frag
// regs afA/afB, bfr n01/n23 alternation), then MFMA(p).  NO explicit lgkm,
// NO asm memory fences -- compiler emits counted lgkm per register dep, so
// LDS service of p+1's reads overlaps MFMA(p).  sched_barrier(0) after each
// s_barrier stops cross-phase code motion at zero runtime cost.
// vmcnt(6) (clobber-free) at even phases only; coverage proof: every staged
// region is retired by a vmcnt >=1 phase before its read-issue, slack 3-5
// phases.  Prologue stages A00,B00,A01,B01,A10,B10,A11 then vmcnt(6).

#define LDSA(c,kk) (lds + (c)*65536 + (kk)*16384)
#define LDSB(c,kk) (lds + (c)*65536 + 32768 + (kk)*16384)
#define STAGE_A(c,kk,col) do { \
    GLOAD_LDS16(gA0 + (col), LDSA(c,kk) + wave*1024); \
    GLOAD_LDS16(gA1 + (col), LDSA(c,kk) + 8192 + wave*1024); } while(0)
#define STAGE_B(c,kk,col) do { \
    GLOAD_LDS16(gB0 + (col), LDSB(c,kk) + wave*1024); \
    GLOAD_LDS16(gB1 + (col), LDSB(c,kk) + 8192 + wave*1024); } while(0)
#define READ_AF(S,c,kk) do { const char* _p = LDSA(c,kk) + aoff; \
    _Pragma("unroll") for (int m = 0; m < 8; ++m) S[m] = *(const bf16x8*)(_p + m*1024); } while(0)
#define READ_B2(c,kk,n0) do { const char* _p = LDSB(c,kk) + boff; \
    bfr[n0] = *(const bf16x8*)(_p + (n0)*1024); \
    bfr[(n0)+1] = *(const bf16x8*)(_p + ((n0)+1)*1024); } while(0)
#define MF16(S,n0) do { __builtin_amdgcn_s_setprio(1); \
    _Pragma("unroll") for (int m = 0; m < 8; ++m) { \
    acc[m][n0]     = __builtin_amdgcn_mfma_f32_16x16x32_bf16(S[m], bfr[n0],     acc[m][n0],     0,0,0); \
    acc[m][(n0)+1] = __builtin_amdgcn_mfma_f32_16x16x32_bf16(S[m], bfr[(n0)+1], acc[m][(n0)+1], 0,0,0); } \
    __builtin_amdgcn_s_setprio(0); } while(0)

#define BAR __builtin_amdgcn_s_barrier()
#define SB0 __builtin_amdgcn_sched_barrier(0)
#define VM6 asm volatile("s_waitcnt vmcnt(6)")
#define VM0 asm volatile("s_waitcnt vmcnt(0)")

// Phase body: [reads(p+1)][stage][MFMA(p)][vm?][BAR][SB0]
#define ITERX(kb, LAST) do { \
  /*1*/ READ_B2(0,0,2);                   STAGE_B(1,1,(kb)+96);              MF16(afA,0);                        BAR; SB0; \
  /*2*/ READ_AF(afB,0,1); READ_B2(0,1,0); if(!(LAST)) STAGE_A(0,0,(kb)+128); MF16(afA,2); VM6;                   BAR; SB0; \
  /*3*/ READ_B2(0,1,2);                   if(!(LAST)) STAGE_B(0,0,(kb)+128); MF16(afB,0);                        BAR; SB0; \
  /*4*/ READ_AF(afA,1,0); READ_B2(1,0,0); if(!(LAST)) STAGE_A(0,1,(kb)+160); MF16(afB,2); if(LAST) VM0; else VM6; BAR; SB0; \
  /*5*/ READ_B2(1,0,2);                   if(!(LAST)) STAGE_B(0,1,(kb)+160); MF16(afA,0);                        BAR; SB0; \
  /*6*/ READ_AF(afB,1,1); READ_B2(1,1,0); if(!(LAST)) STAGE_A(1,0,(kb)+192); MF16(afA,2); if(!(LAST)) VM6;       BAR; SB0; \
  /*7*/ READ_B2(1,1,2);                   if(!(LAST)) STAGE_B(1,0,(kb)+192); MF16(afB,0);                        BAR; SB0; \
  /*8*/ if(!(LAST)) { READ_AF(afA,0,0); READ_B2(0,0,0); STAGE_A(1,1,(kb)+224); } MF16(afB,2); if(!(LAST)) VM6;   BAR; SB0; \
} while(0)

template<bool OUT_BF16>
__global__ __launch_bounds__(512, 2) void k_gemm256(const ushort* __restrict__ A,
                                                    const ushort* __restrict__ Bt,
                                                    const float* __restrict__ bias,
                                                    void* __restrict__ Cout,
                                                    int N, int NTN) {
    __shared__ __align__(16) char lds[131072];
    const int K = 1024;
    const int tid = threadIdx.x;
    const int wave = tid >> 6, lane = tid & 63;
    const int wr = wave >> 2, wc = wave & 3;
    const int r = lane & 15, q = lane >> 4;

    // bijective XCD swizzle (gridDim.x % 8 == 0)
    const int cpx = gridDim.x >> 3, wg = blockIdx.x;
    const int swz = (wg & 7) * cpx + (wg >> 3);
    const int tm = swz / NTN, tn = swz - tm * NTN;
    const int bm = tm * 256, bn = tn * 256;

    // staging lane pointers (source pre-swizzled: chunk ^= (row>>1)&3)
    const int srow = tid >> 2;                      // 0..127
    const int c16l = (tid & 3) ^ ((srow >> 1) & 3);
    const ushort* gA0 = A  + (size_t)(bm + srow) * K + c16l * 8;
    const ushort* gA1 = gA0 + (size_t)128 * K;
    const ushort* gB0 = Bt + (size_t)(bn + srow) * K + c16l * 8;
    const ushort* gB1 = gB0 + (size_t)128 * K;

    // swizzled ds_read offsets: chunk = q ^ ((row>>1)&3)
    const int chunkx = ((q ^ ((r >> 1) & 3)) << 4);
    const int aoff = (wr * 128 + r) * 64 + chunkx;
    const int boff = (wc * 64 + r) * 64 + chunkx;

    f32x4 acc[8][4];
    #pragma unroll
    for (int m = 0; m < 8; ++m)
        #pragma unroll
        for (int n = 0; n < 4; ++n)
            acc[m][n] = (f32x4){0.f, 0.f, 0.f, 0.f};
    bf16x8 afA[8], afB[8], bfr[4];

    // prologue: stage in exact order A00,B00,A01,B01,A10,B10,A11 (14 loads),
    // vmcnt(6) retires A00,B00,A01,B01; pre-read frags for iter0 phase 1.
    STAGE_A(0,0,0);  STAGE_B(0,0,0);
    STAGE_A(0,1,32); STAGE_B(0,1,32);
    STAGE_A(1,0,64); STAGE_B(1,0,64);
    STAGE_A(1,1,96);
    VM6; BAR; SB0;
    READ_AF(afA,0,0); READ_B2(0,0,0);

    #pragma unroll 1
    for (int i = 0; i < 7; ++i) { ITERX(i * 128, 0); }
    ITERX(896, 1);

    float* Cf = (float*)Cout;
    ushort* Cb = (ushort*)Cout;
    #pragma unroll
    for (int m = 0; m < 8; ++m) {
        int row0 = bm + wr * 128 + m * 16 + q * 4;
        #pragma unroll
        for (int n = 0; n < 4; ++n) {
            int col = bn + wc * 64 + n * 16 + r;
            float bv = bias[col];
            #pragma unroll
            for (int j = 0; j < 4; ++j) {
                float v = acc[m][n][j] + bv;
                if (OUT_BF16) Cb[(size_t)(row0 + j) * N + col] = f2bf(v);
                else          Cf[(size_t)(row0 + j) * N + col] = v;
            }
        }
    }
}

// ---------------- per-token head-mixing attention, MFMA, 1 wave/token ----
// qkv row layout: col = h*192 + {0..63 q, 64..127 k, 128..191 v}
// Swapped QK^T: S^T = mfma16x16x32(A=K, B=Q): lane(r=l&15,g=l>>4) holds
// S[qh=r][kh=4g+j].  Softmax over kh: in-lane (4) + shfl_xor 16,32.
// PV via mfma16x16x32 with K padded to 32: A-frag lane needs P[r][8g+j]
// (j=0..7, zero for g>=2) gathered with 8 shuffles; B-frag = V[kh][d].
__global__ __launch_bounds__(256) void k_attn_mfma(const ushort* __restrict__ qkv,
                                                   ushort* __restrict__ ctx) {
    const int lane = threadIdx.x & 63;
    const size_t tok = (size_t)blockIdx.x * 4 + (threadIdx.x >> 6);
    const ushort* row = qkv + tok * 3072;
    const int r = lane & 15, g = lane >> 4;

    bf16x8 ka[2], qb[2];
    #pragma unroll
    for (int c = 0; c < 2; ++c) {
        ka[c] = *(const bf16x8*)(row + r * 192 + 64 + c * 32 + g * 8);  // K[r][d]
        qb[c] = *(const bf16x8*)(row + r * 192 +      c * 32 + g * 8);  // Q[r][d]
    }
    f32x4 st = (f32x4){0.f, 0.f, 0.f, 0.f};
    st = __builtin_amdgcn_mfma_f32_16x16x32_bf16(ka[0], qb[0], st, 0, 0, 0);
    st = __builtin_amdgcn_mfma_f32_16x16x32_bf16(ka[1], qb[1], st, 0, 0, 0);

    float s[4];
    #pragma unroll
    for (int j = 0; j < 4; ++j) s[j] = st[j] * 0.125f;
    float m = fmaxf(fmaxf(s[0], s[1]), fmaxf(s[2], s[3]));
    m = fmaxf(m, __shfl_xor(m, 16));
    m = fmaxf(m, __shfl_xor(m, 32));
    float p[4], sum = 0.f;
    #pragma unroll
    for (int j = 0; j < 4; ++j) { p[j] = __expf(s[j] - m); sum += p[j]; }
    sum += __shfl_xor(sum, 16);
    sum += __shfl_xor(sum, 32);
    float inv = 1.f / sum;
    #pragma unroll
    for (int j = 0; j < 4; ++j) p[j] *= inv;

    // gather A-frag: lane needs P[r][8g+j]; source lane r+32g (j0-3), +16 (j4-7)
    const bool gok = (g < 2);
    const int src0 = (r + 32 * g) & 63, src1 = (src0 + 16) & 63;
    bf16x8 pa;
    #pragma unroll
    for (int j = 0; j < 4; ++j) {
        float a0 = __shfl(p[j], src0, 64);
        float a1 = __shfl(p[j], src1, 64);
        pa[j]     = (short)(gok ? f2bf(a0) : (ushort)0);
        pa[4 + j] = (short)(gok ? f2bf(a1) : (ushort)0);
    }

    #pragma unroll
    for (int db = 0; db < 4; ++db) {
        bf16x8 vb;
        #pragma unroll
        for (int j = 0; j < 8; ++j)
            vb[j] = (short)(gok ? row[(g * 8 + j) * 192 + 128 + db * 16 + r] : (ushort)0);
        f32x4 o = (f32x4){0.f, 0.f, 0.f, 0.f};
        o = __builtin_amdgcn_mfma_f32_16x16x32_bf16(pa, vb, o, 0, 0, 0);
        #pragma unroll
        for (int j = 0; j < 4; ++j)
            ctx[tok * 1024 + (4 * g + j) * 64 + db * 16 + r] = f2bf(o[j]);
    }
}

extern "C" void kernel_launch(void* const* d_in, const int* in_sizes, int n_in,
                              void* d_out, int out_size, void* d_ws, size_t ws_size,
                              hipStream_t stream) {
    const float* x     = (const float*)d_in[0];
    const float* W_qkv = (const float*)d_in[1];
    const float* b_qkv = (const float*)d_in[2];
    const float* W_out = (const float*)d_in[3];
    const float* b_out = (const float*)d_in[4];

    const int M = 16384, D = 1024, N3 = 3072;

    ushort* xb   = (ushort*)d_ws;
    ushort* wqkT = xb + (size_t)M * D;
    ushort* woT  = wqkT + (size_t)N3 * D;
    ushort* qkv  = woT + (size_t)D * D;
    ushort* ctx  = xb;  // xb dead after GEMM1; reuse for context

    hipLaunchKernelGGL(k_cvt_bf16, dim3((M * D / 4 + 255) / 256), dim3(256), 0, stream,
                       x, xb, M * D / 4);
    hipLaunchKernelGGL(k_transpose_cvt, dim3(N3 / 32, D / 32), dim3(32, 8), 0, stream,
                       W_qkv, wqkT, D, N3);
    hipLaunchKernelGGL(k_transpose_cvt, dim3(D / 32, D / 32), dim3(32, 8), 0, stream,
                       W_out, woT, D, D);
    hipLaunchKernelGGL((k_gemm256<true>), dim3((N3 / 256) * (M / 256)), dim3(512), 0, stream,
                       xb, wqkT, b_qkv, (void*)qkv, N3, N3 / 256);
    hipLaunchKernelGGL(k_attn_mfma, dim3(M / 4), dim3(256), 0, stream, qkv, ctx);
    hipLaunchKernelGGL((k_gemm256<false>), dim3((D / 256) * (M / 256)), dim3(512), 0, stream,
                       ctx, woT, b_out, d_out, D, D / 256);
}